// Round 14
// baseline (87.904 us; speedup 1.0000x reference)
//
#include <hip/hip_runtime.h>

// Problem constants (fixed by setup_inputs)
#define B_    16
#define N_    262144            // 2^18 pixels per image
#define NC    150               // classes
#define NP    4096              // pred segment ids
#define T_    (B_ * NC)         // 2400 distinct target ids
#define TOTAL (B_ * N_)         // 4,194,304 pixels

// partition: 256 parent buckets (pred>>4)
#define PBKT       256
#define PCAP       18432        // mean 16384, +16 sigma
#define KEY_SHIFT  16           // local key = (p&15)*2400 + t < 38400 < 2^16
#define P1_BLOCKS  1024
#define P1_PIX     (TOTAL / P1_BLOCKS)   // 4096 pixels per block (one image)

// iou: 4 co-blocks per parent bucket, each owns 4 pred rows
#define QT         9600         // local keys per quadrant (4*2400)

// gCount padded: one counter per 256 B (own L2 line) -> no atomic serialization
#define CSTRIDE    64
#define CTRS_ONE   (PBKT * CSTRIDE + T_)   // one set: 16384 + 2400 = 18784 u32
#define NCOUNTERS  (2 * CTRS_ONE)          // real + shadow

typedef unsigned int u32;
typedef unsigned short u16;

// ---------------------------------------------------------------------------
// Kernel 0: zero the counters (real + shadow sets)
// ---------------------------------------------------------------------------
__global__ __launch_bounds__(256) void init_kernel(u32* __restrict__ ctrs) {
    int i = blockIdx.x * 256 + threadIdx.x;
    if (i < NCOUNTERS) ctrs[i] = 0;
}

// ---------------------------------------------------------------------------
// Kernel 1: radix-split pixels into 256 parent buckets (+ fused n_tgt).
// MEASUREMENT ROUND: launched twice (second into shadow buffers) so
// partition_dur ~= this_round_total - 62.4us (R12 baseline).
// ---------------------------------------------------------------------------
__global__ __launch_bounds__(256, 8) void partition_kernel(const int* __restrict__ pred,
                                                           const int* __restrict__ tgt,
                                                           u16* __restrict__ records,
                                                           u32* __restrict__ gCount,
                                                           u32* __restrict__ gNT) {
    __shared__ u32 cursor[PBKT];     // counts in phase A, cursors in phase C (1 KB)
    __shared__ u32 goff[PBKT];       // gbase - lstart (1 KB)
    __shared__ u32 nth[NC];          // class histogram (600 B)
    __shared__ u32 wsum[4];
    __shared__ u32 staging[P1_PIX];  // 16 KB

    int tid = threadIdx.x;
    cursor[tid] = 0;
    if (tid < NC) nth[tid] = 0;
    __syncthreads();

    int base = blockIdx.x * P1_PIX;
    int b_img = base >> 18;                  // constant per block
    const int4* pred4 = (const int4*)pred;
    const int4* tgt4  = (const int4*)tgt;

    // ---- phase A: count buckets + classes (no key storage) ----
    #pragma unroll
    for (int k = 0; k < 4; ++k) {
        int vi = (base >> 2) + k * 256 + tid;
        int4 pv = pred4[vi];
        int4 tv = tgt4[vi];
        atomicAdd(&cursor[(u32)pv.x >> 4], 1u);
        atomicAdd(&cursor[(u32)pv.y >> 4], 1u);
        atomicAdd(&cursor[(u32)pv.z >> 4], 1u);
        atomicAdd(&cursor[(u32)pv.w >> 4], 1u);
        atomicAdd(&nth[tv.x], 1u);
        atomicAdd(&nth[tv.y], 1u);
        atomicAdd(&nth[tv.z], 1u);
        atomicAdd(&nth[tv.w], 1u);
    }
    __syncthreads();

    // ---- phase B: exclusive scan (wave shfl) + global base assignment ----
    {
        u32 myc = cursor[tid];
        u32 v = myc;
        #pragma unroll
        for (int o = 1; o < 64; o <<= 1) {
            u32 t = __shfl_up(v, o);
            if ((tid & 63) >= o) v += t;
        }
        if ((tid & 63) == 63) wsum[tid >> 6] = v;
        __syncthreads();
        u32 woff = 0;
        #pragma unroll
        for (int w = 0; w < 3; ++w) woff += (w < (tid >> 6)) ? wsum[w] : 0;
        u32 ex = v + woff - myc;                 // exclusive prefix
        cursor[tid] = ex;                        // becomes scatter cursor
        u32 gb = atomicAdd(&gCount[tid * CSTRIDE], myc);
        goff[tid] = gb - ex;
    }
    if (tid < NC && nth[tid]) atomicAdd(&gNT[b_img * NC + tid], nth[tid]);
    __syncthreads();

    // ---- phase C: re-read inputs (L2/L3-hot), recompute keys, scatter ----
    #pragma unroll
    for (int k = 0; k < 4; ++k) {
        int vi = (base >> 2) + k * 256 + tid;
        int4 pv = pred4[vi];
        int4 tv = tgt4[vi];
        int pe[4] = {pv.x, pv.y, pv.z, pv.w};
        int te[4] = {tv.x, tv.y, tv.z, tv.w};
        #pragma unroll
        for (int e = 0; e < 4; ++e) {
            int p = pe[e];
            u32 bkt = (u32)(p >> 4);
            u32 lk  = (u32)((p & 15) * T_ + b_img * NC + te[e]);
            u32 pos = atomicAdd(&cursor[bkt], 1u);
            staging[pos] = (bkt << KEY_SHIFT) | lk;
        }
    }
    __syncthreads();

    // ---- phase D: coalesced flush: ~16-record (32 B) runs per bucket ----
    for (int r = tid; r < P1_PIX; r += 256) {
        u32 v = staging[r];
        u32 bkt = v >> KEY_SHIFT;
        u32 gp = goff[bkt] + (u32)r;             // = gbase + (r - lstart)
        if (gp < PCAP) records[(size_t)bkt * PCAP + gp] = (u16)(v & 0xFFFFu);
    }
}

// ---------------------------------------------------------------------------
// Kernel 2: 4 co-blocks per parent bucket, each owning 4 pred rows.
// ---------------------------------------------------------------------------
__global__ __launch_bounds__(256, 7) void iou_kernel(const u16* __restrict__ records,
                                                     const u32* __restrict__ gCount,
                                                     const u32* __restrict__ gNT,
                                                     const float* __restrict__ targets,
                                                     float* __restrict__ out) {
    __shared__ u32 hist[QT / 2];              // 4800 words = 19.2 KB
    __shared__ float npred_s[4];
    __shared__ float iou_pc[4][NC];           // 2.4 KB
    __shared__ float4 wred[4];                // per-wave partial denominators

    int tid = threadIdx.x;
    int bkt = blockIdx.x & 255;               // XCD co-location swizzle
    int q   = blockIdx.x >> 8;
    u32 lo = (u32)(q * QT);

    // vectorized hist zero
    {
        uint4 z4 = make_uint4(0u, 0u, 0u, 0u);
        uint4* h4 = (uint4*)hist;
        for (int j = tid; j < QT / 8; j += 256) h4[j] = z4;
    }
    __syncthreads();

    u32 cnt = gCount[bkt * CSTRIDE];
    if (cnt > PCAP) cnt = PCAP;
    const u16* rec = records + (size_t)bkt * PCAP;

    // vectorized scan (8 B/lane), 1-deep prefetch, single-compare filter
    u32 nv4 = cnt >> 2;
    const ushort4* rec4 = (const ushort4*)rec;
    {
        u32 r = tid;
        ushort4 cur;
        if (r < nv4) cur = rec4[r];
        for (; r < nv4; ) {
            u32 rn = r + 256;
            ushort4 nxt;
            if (rn < nv4) nxt = rec4[rn];
            u32 e[4] = {cur.x, cur.y, cur.z, cur.w};
            #pragma unroll
            for (int i = 0; i < 4; ++i) {
                u32 lk = e[i] - lo;
                if (lk < (u32)QT)
                    atomicAdd(&hist[lk >> 1], (lk & 1u) ? 65536u : 1u);
            }
            cur = nxt;
            r = rn;
        }
    }
    for (u32 r = (nv4 << 2) + tid; r < cnt; r += 256) {
        u32 lk = (u32)rec[r] - lo;
        if (lk < (u32)QT)
            atomicAdd(&hist[lk >> 1], (lk & 1u) ? 65536u : 1u);
    }
    __syncthreads();

    // n_pred row sums: 4 waves, one pred row each (1200 words)
    {
        int pl = tid >> 6, lane = tid & 63;
        u32 s = 0;
        for (int w = lane; w < T_ / 2; w += 64) {
            u32 v = hist[pl * (T_ / 2) + w];
            s += (v & 0xFFFFu) + (v >> 16);
        }
        #pragma unroll
        for (int o = 32; o > 0; o >>= 1) s += __shfl_xor(s, o);
        if (lane == 0) npred_s[pl] = (float)s;
    }
    __syncthreads();

    // iou_pc[pl][c] = sum_b O/(n_pred + n_tgt - O); gNT reads are L1-hot
    for (int idx = tid; idx < 4 * NC; idx += 256) {
        int pl = idx / NC, cls = idx - pl * NC;
        float np = npred_s[pl];
        float acc = 0.f;
        #pragma unroll
        for (int b = 0; b < B_; ++b) {
            int lk = pl * T_ + b * NC + cls;
            u32 w = hist[lk >> 1];
            u32 v = (lk & 1) ? (w >> 16) : (w & 0xFFFFu);
            if (v) {
                float fv = (float)v;
                acc += fv * __builtin_amdgcn_rcpf(np + (float)gNT[b * NC + cls] - fv);
            }
        }
        iou_pc[pl][cls] = acc;
    }
    __syncthreads();

    // matmul with targets (each element read once for all 4 rows)
    float o0 = 0.f, o1 = 0.f, o2 = 0.f, o3 = 0.f;
    if (tid < NC) {
        for (int k = 0; k < NC; ++k) {
            float tv = targets[k * NC + tid];
            o0 += iou_pc[0][k] * tv;
            o1 += iou_pc[1][k] * tv;
            o2 += iou_pc[2][k] * tv;
            o3 += iou_pc[3][k] * tv;
        }
    }

    // denominator: wave shfl reduce -> 4 partials -> broadcast sum
    {
        float4 v = (tid < NC) ? make_float4(o0, o1, o2, o3)
                              : make_float4(0.f, 0.f, 0.f, 0.f);
        #pragma unroll
        for (int o = 32; o > 0; o >>= 1) {
            v.x += __shfl_xor(v.x, o);
            v.y += __shfl_xor(v.y, o);
            v.z += __shfl_xor(v.z, o);
            v.w += __shfl_xor(v.w, o);
        }
        if ((tid & 63) == 0) wred[tid >> 6] = v;
    }
    __syncthreads();
    float4 den;
    {
        float4 a = wred[0], b = wred[1], c = wred[2], d = wred[3];
        den = make_float4(a.x + b.x + c.x + d.x, a.y + b.y + c.y + d.y,
                          a.z + b.z + c.z + d.z, a.w + b.w + c.w + d.w);
    }

    if (tid < NC) {
        size_t ob = (size_t)(bkt * 16 + q * 4) * NC + tid;
        out[ob + 0 * NC] = o0 * __builtin_amdgcn_rcpf(den.x);
        out[ob + 1 * NC] = o1 * __builtin_amdgcn_rcpf(den.y);
        out[ob + 2 * NC] = o2 * __builtin_amdgcn_rcpf(den.z);
        out[ob + 3 * NC] = o3 * __builtin_amdgcn_rcpf(den.w);
    }
}

// ---------------------------------------------------------------------------
extern "C" void kernel_launch(void* const* d_in, const int* in_sizes, int n_in,
                              void* d_out, int out_size, void* d_ws, size_t ws_size,
                              hipStream_t stream) {
    const int*   pred    = (const int*)d_in[0];
    const int*   tgt     = (const int*)d_in[1];
    const float* targets = (const float*)d_in[2];
    float*       out     = (float*)d_out;

    u32* gCount   = (u32*)d_ws;                         // 256*CSTRIDE
    u32* gNT      = gCount + PBKT * CSTRIDE;            // 2400
    u32* gCount2  = gNT + T_;                           // shadow set
    u32* gNT2     = gCount2 + PBKT * CSTRIDE;
    u16* records  = (u16*)(gNT2 + T_);                  // 9.4 MB
    u16* records2 = records + (size_t)PBKT * PCAP;      // shadow 9.4 MB

    init_kernel<<<(NCOUNTERS + 255) / 256, 256, 0, stream>>>((u32*)d_ws);
    partition_kernel<<<P1_BLOCKS, 256, 0, stream>>>(pred, tgt, records, gCount, gNT);
    // MEASUREMENT: second partition into shadow buffers (identical work).
    // partition_dur ~= this_round_total - 62.4us (R12 baseline).
    partition_kernel<<<P1_BLOCKS, 256, 0, stream>>>(pred, tgt, records2, gCount2, gNT2);
    iou_kernel<<<PBKT * 4, 256, 0, stream>>>(records, gCount, gNT, targets, out);
}

// Round 15
// 68.514 us; speedup vs baseline: 1.2830x; 1.2830x over previous
//
#include <hip/hip_runtime.h>

// Problem constants (fixed by setup_inputs)
#define B_    16
#define N_    262144            // 2^18 pixels per image
#define NC    150               // classes
#define NP    4096              // pred segment ids
#define T_    (B_ * NC)         // 2400 distinct target ids
#define TOTAL (B_ * N_)         // 4,194,304 pixels

#define PBKT   256              // parent buckets (pred>>4)
#define SEGS   1024             // partition blocks
#define SLOT   48               // record slots per (block,bucket); mean 16, +8 sigma
#define P1_PIX (TOTAL / SEGS)   // 4096 pixels per block (one image)

// iou: 4 co-blocks per parent bucket, each owns 4 pred rows
#define QT     9600             // local keys per quadrant (4*2400)

typedef unsigned int u32;
typedef unsigned short u16;

// ---------------------------------------------------------------------------
// Kernel 1: direct-scatter partition. No init, no global counters, no staging.
// Records land in fixed per-(block,bucket) 48-slot segments (L2-resident per
// block). 2 LDS atomics/pixel (was 3) and ~2 KB LDS -> high occupancy.
// nt partials written non-atomically (no pre-zero needed anywhere).
// ---------------------------------------------------------------------------
__global__ __launch_bounds__(256) void part_direct(const int* __restrict__ pred,
                                                   const int* __restrict__ tgt,
                                                   u16* __restrict__ rec2d,
                                                   u32* __restrict__ cntArr,
                                                   u16* __restrict__ ntPart) {
    __shared__ u32 cnt[PBKT];
    __shared__ u32 nth[NC];

    int tid = threadIdx.x;
    int blk = blockIdx.x;
    cnt[tid] = 0;
    if (tid < NC) nth[tid] = 0;
    __syncthreads();

    int base = blk * P1_PIX;
    int b_img = base >> 18;                  // constant per block
    const int4* pred4 = (const int4*)pred;
    const int4* tgt4  = (const int4*)tgt;

    #pragma unroll
    for (int k = 0; k < 4; ++k) {
        int vi = (base >> 2) + k * 256 + tid;
        int4 pv = pred4[vi];
        int4 tv = tgt4[vi];
        int pe[4] = {pv.x, pv.y, pv.z, pv.w};
        int te[4] = {tv.x, tv.y, tv.z, tv.w};
        #pragma unroll
        for (int e = 0; e < 4; ++e) {
            int p = pe[e];
            u32 bkt = (u32)(p >> 4);
            u32 lk  = (u32)((p & 15) * T_ + b_img * NC + te[e]);
            u32 pos = atomicAdd(&cnt[bkt], 1u);
            if (pos < SLOT)
                rec2d[((size_t)blk * PBKT + bkt) * SLOT + pos] = (u16)lk;
            atomicAdd(&nth[te[e]], 1u);
        }
    }
    __syncthreads();

    cntArr[blk * PBKT + tid] = cnt[tid];
    if (tid < NC) ntPart[blk * 160 + tid] = (u16)nth[tid];
}

// ---------------------------------------------------------------------------
// Kernel 2: reduce nt partials -> gNT. One block per image, single-writer,
// non-atomic (so gNT needs no pre-zeroing either).
// ---------------------------------------------------------------------------
__global__ __launch_bounds__(256) void ntreduce(const u16* __restrict__ ntPart,
                                                u32* __restrict__ gNT) {
    int img = blockIdx.x;
    int c = threadIdx.x;
    if (c < NC) {
        u32 s = 0;
        #pragma unroll 8
        for (int b2 = 0; b2 < SEGS / B_; ++b2)      // 64 partition blocks per image
            s += ntPart[(img * (SEGS / B_) + b2) * 160 + c];
        gNT[img * NC + c] = s;
    }
}

// ---------------------------------------------------------------------------
// Kernel 3: 4 co-blocks per parent bucket, each owning 4 pred rows.
// Scans the bucket's 1024 segments via cntArr (reads only live records).
// bkt = blockIdx&255 keeps co-blocks of a bucket on one XCD.
// ---------------------------------------------------------------------------
__global__ __launch_bounds__(256, 7) void iou_kernel(const u16* __restrict__ rec2d,
                                                     const u32* __restrict__ cntArr,
                                                     const u32* __restrict__ gNT,
                                                     const float* __restrict__ targets,
                                                     float* __restrict__ out) {
    __shared__ u32 hist[QT / 2];              // 4800 words = 19.2 KB
    __shared__ float npred_s[4];
    __shared__ float iou_pc[4][NC];           // 2.4 KB
    __shared__ float4 wred[4];                // per-wave partial denominators

    int tid = threadIdx.x;
    int bkt = blockIdx.x & 255;               // XCD co-location swizzle
    int q   = blockIdx.x >> 8;
    u32 lo = (u32)(q * QT);

    // vectorized hist zero
    {
        uint4 z4 = make_uint4(0u, 0u, 0u, 0u);
        uint4* h4 = (uint4*)hist;
        for (int j = tid; j < QT / 8; j += 256) h4[j] = z4;
    }
    __syncthreads();

    // scan: each thread walks whole segments (16B-aligned, 96 B slots)
    for (int s = tid; s < SEGS; s += 256) {   // 4 segments per thread
        u32 n = cntArr[s * PBKT + bkt];
        if (n > SLOT) n = SLOT;
        const uint4* seg4 = (const uint4*)(rec2d + ((size_t)s * PBKT + bkt) * SLOT);
        for (u32 j8 = 0; j8 * 8 < n; ++j8) {
            uint4 v = seg4[j8];
            u32 words[4] = {v.x, v.y, v.z, v.w};
            u32 bi = j8 * 8;
            #pragma unroll
            for (int w = 0; w < 4; ++w) {
                #pragma unroll
                for (int h = 0; h < 2; ++h) {
                    u32 idx = bi + (u32)(w * 2 + h);
                    u32 rec = (words[w] >> (h * 16)) & 0xFFFFu;
                    if (idx < n) {
                        u32 lk = rec - lo;
                        if (lk < (u32)QT)
                            atomicAdd(&hist[lk >> 1], (lk & 1u) ? 65536u : 1u);
                    }
                }
            }
        }
    }
    __syncthreads();

    // n_pred row sums: 4 waves, one pred row each (1200 words)
    {
        int pl = tid >> 6, lane = tid & 63;
        u32 s = 0;
        for (int w = lane; w < T_ / 2; w += 64) {
            u32 v = hist[pl * (T_ / 2) + w];
            s += (v & 0xFFFFu) + (v >> 16);
        }
        #pragma unroll
        for (int o = 32; o > 0; o >>= 1) s += __shfl_xor(s, o);
        if (lane == 0) npred_s[pl] = (float)s;
    }
    __syncthreads();

    // iou_pc[pl][c] = sum_b O/(n_pred + n_tgt - O); gNT reads are L1-hot
    for (int idx = tid; idx < 4 * NC; idx += 256) {
        int pl = idx / NC, cls = idx - pl * NC;
        float np = npred_s[pl];
        float acc = 0.f;
        #pragma unroll
        for (int b = 0; b < B_; ++b) {
            int lk = pl * T_ + b * NC + cls;
            u32 w = hist[lk >> 1];
            u32 v = (lk & 1) ? (w >> 16) : (w & 0xFFFFu);
            if (v) {
                float fv = (float)v;
                acc += fv * __builtin_amdgcn_rcpf(np + (float)gNT[b * NC + cls] - fv);
            }
        }
        iou_pc[pl][cls] = acc;
    }
    __syncthreads();

    // matmul with targets (each element read once for all 4 rows)
    float o0 = 0.f, o1 = 0.f, o2 = 0.f, o3 = 0.f;
    if (tid < NC) {
        for (int k = 0; k < NC; ++k) {
            float tv = targets[k * NC + tid];
            o0 += iou_pc[0][k] * tv;
            o1 += iou_pc[1][k] * tv;
            o2 += iou_pc[2][k] * tv;
            o3 += iou_pc[3][k] * tv;
        }
    }

    // denominator: wave shfl reduce -> 4 partials -> broadcast sum
    {
        float4 v = (tid < NC) ? make_float4(o0, o1, o2, o3)
                              : make_float4(0.f, 0.f, 0.f, 0.f);
        #pragma unroll
        for (int o = 32; o > 0; o >>= 1) {
            v.x += __shfl_xor(v.x, o);
            v.y += __shfl_xor(v.y, o);
            v.z += __shfl_xor(v.z, o);
            v.w += __shfl_xor(v.w, o);
        }
        if ((tid & 63) == 0) wred[tid >> 6] = v;
    }
    __syncthreads();
    float4 den;
    {
        float4 a = wred[0], b = wred[1], c = wred[2], d = wred[3];
        den = make_float4(a.x + b.x + c.x + d.x, a.y + b.y + c.y + d.y,
                          a.z + b.z + c.z + d.z, a.w + b.w + c.w + d.w);
    }

    if (tid < NC) {
        size_t ob = (size_t)(bkt * 16 + q * 4) * NC + tid;
        out[ob + 0 * NC] = o0 * __builtin_amdgcn_rcpf(den.x);
        out[ob + 1 * NC] = o1 * __builtin_amdgcn_rcpf(den.y);
        out[ob + 2 * NC] = o2 * __builtin_amdgcn_rcpf(den.z);
        out[ob + 3 * NC] = o3 * __builtin_amdgcn_rcpf(den.w);
    }
}

// ---------------------------------------------------------------------------
extern "C" void kernel_launch(void* const* d_in, const int* in_sizes, int n_in,
                              void* d_out, int out_size, void* d_ws, size_t ws_size,
                              hipStream_t stream) {
    const int*   pred    = (const int*)d_in[0];
    const int*   tgt     = (const int*)d_in[1];
    const float* targets = (const float*)d_in[2];
    float*       out     = (float*)d_out;

    // ws layout (nothing needs pre-zeroing):
    u16* rec2d  = (u16*)d_ws;                              // 1024*256*48 u16 = 25.2 MB
    u32* cntArr = (u32*)(rec2d + (size_t)SEGS * PBKT * SLOT);  // 1024*256 u32 = 1 MB
    u16* ntPart = (u16*)(cntArr + SEGS * PBKT);            // 1024*160 u16 = 320 KB
    u32* gNT    = (u32*)(ntPart + SEGS * 160);             // 2400 u32

    part_direct<<<SEGS, 256, 0, stream>>>(pred, tgt, rec2d, cntArr, ntPart);
    ntreduce<<<B_, 256, 0, stream>>>(ntPart, gNT);
    iou_kernel<<<PBKT * 4, 256, 0, stream>>>(rec2d, cntArr, gNT, targets, out);
}

// Round 16
// 54.801 us; speedup vs baseline: 1.6041x; 1.2502x over previous
//
#include <hip/hip_runtime.h>

// Problem constants (fixed by setup_inputs)
#define B_    16
#define N_    262144            // 2^18 pixels per image
#define NC    150               // classes
#define NP    4096              // pred segment ids
#define T_    (B_ * NC)         // 2400 distinct target ids
#define TOTAL (B_ * N_)         // 4,194,304 pixels

#define PBKT   256              // parent buckets (pred>>4)
#define SEGS   1024             // partition blocks
#define SEGPIX 4096             // pixels (records) per segment
// iou: 4 co-blocks per parent bucket, each owns 4 pred rows
#define QT     9600             // local keys per quadrant (4*2400)

typedef unsigned int u32;
typedef unsigned short u16;

// ---------------------------------------------------------------------------
// Kernel 1: staged radix-split, single input pass, rank-fused (2 LDS atomics
// per pixel, no cursor atomic), fully contiguous flush. Nothing pre-zeroed.
// Per block: records -> recSeg[blk*4096 ..] sorted by bucket;
//            meta[blk*256+bkt] = (lstart<<16)|cnt; ntPart[blk*160+c].
// LDS ~34.6 KB -> 4 blocks/CU.
// ---------------------------------------------------------------------------
__global__ __launch_bounds__(256) void partition_kernel(const int* __restrict__ pred,
                                                        const int* __restrict__ tgt,
                                                        u16* __restrict__ recSeg,
                                                        u32* __restrict__ metaArr,
                                                        u16* __restrict__ ntPart) {
    __shared__ u32 keybuf[SEGPIX];   // 16 KB: (bkt<<16)|lk
    __shared__ u16 rankbuf[SEGPIX];  // 8 KB: within-(block,bucket) rank
    __shared__ u16 staging[SEGPIX];  // 8 KB: bucket-sorted u16 records
    __shared__ u32 cnt[PBKT];        // 1 KB
    __shared__ u32 lstart[PBKT];     // 1 KB
    __shared__ u32 nth[NC];          // 600 B
    __shared__ u32 wsum[4];

    int tid = threadIdx.x;
    int blk = blockIdx.x;
    cnt[tid] = 0;
    if (tid < NC) nth[tid] = 0;
    __syncthreads();

    int base = blk * SEGPIX;
    int b_img = base >> 18;                  // constant per block
    const int4* pred4 = (const int4*)pred;
    const int4* tgt4  = (const int4*)tgt;

    // ---- phase A: read once; key + rank into LDS; count + class hist ----
    #pragma unroll
    for (int k = 0; k < 4; ++k) {
        int vi = (base >> 2) + k * 256 + tid;
        int4 pv = pred4[vi];
        int4 tv = tgt4[vi];
        int pe[4] = {pv.x, pv.y, pv.z, pv.w};
        int te[4] = {tv.x, tv.y, tv.z, tv.w};
        #pragma unroll
        for (int e = 0; e < 4; ++e) {
            int p = pe[e];
            u32 bkt = (u32)(p >> 4);
            u32 lk  = (u32)((p & 15) * T_ + b_img * NC + te[e]);
            int flat = (k * 256 + tid) * 4 + e;
            u32 rank = atomicAdd(&cnt[bkt], 1u);
            keybuf[flat]  = (bkt << 16) | lk;
            rankbuf[flat] = (u16)rank;
            atomicAdd(&nth[te[e]], 1u);
        }
    }
    __syncthreads();

    // ---- phase B: exclusive scan over bucket counts (wave shfl) ----
    {
        u32 myc = cnt[tid];
        u32 v = myc;
        #pragma unroll
        for (int o = 1; o < 64; o <<= 1) {
            u32 t = __shfl_up(v, o);
            if ((tid & 63) >= o) v += t;
        }
        if ((tid & 63) == 63) wsum[tid >> 6] = v;
        __syncthreads();
        u32 woff = 0;
        #pragma unroll
        for (int w = 0; w < 3; ++w) woff += (w < (tid >> 6)) ? wsum[w] : 0;
        u32 ex = v + woff - myc;                 // exclusive prefix
        lstart[tid] = ex;
        metaArr[blk * PBKT + tid] = (ex << 16) | myc;   // coalesced
    }
    if (tid < NC) ntPart[blk * 160 + tid] = (u16)nth[tid];
    __syncthreads();

    // ---- phase C: rank-based scatter into staging (no atomics) ----
    #pragma unroll
    for (int k = 0; k < 16; ++k) {
        int flat = tid * 16 + k;
        u32 v = keybuf[flat];
        staging[lstart[v >> 16] + (u32)rankbuf[flat]] = (u16)(v & 0xFFFFu);
    }
    __syncthreads();

    // ---- phase D: contiguous vectorized flush (8 KB as 512 uint4) ----
    {
        const uint4* s4 = (const uint4*)staging;
        uint4* d4 = (uint4*)(recSeg + (size_t)blk * SEGPIX);
        d4[tid]       = s4[tid];
        d4[tid + 256] = s4[tid + 256];
    }
}

// ---------------------------------------------------------------------------
// Kernel 2: reduce nt partials -> gNT. Single-writer, no atomics, no init.
// ---------------------------------------------------------------------------
__global__ __launch_bounds__(256) void ntreduce(const u16* __restrict__ ntPart,
                                                u32* __restrict__ gNT) {
    int img = blockIdx.x;
    int c = threadIdx.x;
    if (c < NC) {
        u32 s = 0;
        #pragma unroll 8
        for (int b2 = 0; b2 < SEGS / B_; ++b2)      // 64 partition blocks per image
            s += ntPart[(img * (SEGS / B_) + b2) * 160 + c];
        gNT[img * NC + c] = s;
    }
}

// ---------------------------------------------------------------------------
// Kernel 3: 4 co-blocks per parent bucket, each owning 4 pred rows.
// Walks per-segment (lstart,cnt) runs via metaArr; aligned uint4 reads.
// bkt = blockIdx&255 keeps co-blocks of one bucket on one XCD.
// ---------------------------------------------------------------------------
__global__ __launch_bounds__(256, 7) void iou_kernel(const u16* __restrict__ recSeg,
                                                     const u32* __restrict__ metaArr,
                                                     const u32* __restrict__ gNT,
                                                     const float* __restrict__ targets,
                                                     float* __restrict__ out) {
    __shared__ u32 hist[QT / 2];              // 4800 words = 19.2 KB
    __shared__ float npred_s[4];
    __shared__ float iou_pc[4][NC];           // 2.4 KB
    __shared__ float4 wred[4];                // per-wave partial denominators

    int tid = threadIdx.x;
    int bkt = blockIdx.x & 255;               // XCD co-location swizzle
    int q   = blockIdx.x >> 8;
    u32 lo = (u32)(q * QT);

    // vectorized hist zero
    {
        uint4 z4 = make_uint4(0u, 0u, 0u, 0u);
        uint4* h4 = (uint4*)hist;
        for (int j = tid; j < QT / 8; j += 256) h4[j] = z4;
    }
    __syncthreads();

    // scan: 4 segments per thread; aligned uint4 window over [lstart, lstart+cnt)
    for (int s = tid; s < SEGS; s += 256) {
        u32 m  = metaArr[s * PBKT + bkt];
        u32 ls = m >> 16;
        u32 n  = m & 0xFFFFu;
        if (!n) continue;
        u32 je = ls + n;
        const u16* segp = recSeg + (size_t)s * SEGPIX;
        for (u32 j = ls & ~7u; j < je; j += 8) {
            uint4 v = *(const uint4*)(segp + j);
            u32 words[4] = {v.x, v.y, v.z, v.w};
            #pragma unroll
            for (int w = 0; w < 4; ++w) {
                #pragma unroll
                for (int h = 0; h < 2; ++h) {
                    u32 idx = j + (u32)(w * 2 + h);
                    if (idx >= ls && idx < je) {
                        u32 lk = ((words[w] >> (h * 16)) & 0xFFFFu) - lo;
                        if (lk < (u32)QT)
                            atomicAdd(&hist[lk >> 1], (lk & 1u) ? 65536u : 1u);
                    }
                }
            }
        }
    }
    __syncthreads();

    // n_pred row sums: 4 waves, one pred row each (1200 words)
    {
        int pl = tid >> 6, lane = tid & 63;
        u32 s = 0;
        for (int w = lane; w < T_ / 2; w += 64) {
            u32 v = hist[pl * (T_ / 2) + w];
            s += (v & 0xFFFFu) + (v >> 16);
        }
        #pragma unroll
        for (int o = 32; o > 0; o >>= 1) s += __shfl_xor(s, o);
        if (lane == 0) npred_s[pl] = (float)s;
    }
    __syncthreads();

    // iou_pc[pl][c] = sum_b O/(n_pred + n_tgt - O); gNT reads are L1-hot
    for (int idx = tid; idx < 4 * NC; idx += 256) {
        int pl = idx / NC, cls = idx - pl * NC;
        float np = npred_s[pl];
        float acc = 0.f;
        #pragma unroll
        for (int b = 0; b < B_; ++b) {
            int lk = pl * T_ + b * NC + cls;
            u32 w = hist[lk >> 1];
            u32 v = (lk & 1) ? (w >> 16) : (w & 0xFFFFu);
            if (v) {
                float fv = (float)v;
                acc += fv * __builtin_amdgcn_rcpf(np + (float)gNT[b * NC + cls] - fv);
            }
        }
        iou_pc[pl][cls] = acc;
    }
    __syncthreads();

    // matmul with targets (each element read once for all 4 rows)
    float o0 = 0.f, o1 = 0.f, o2 = 0.f, o3 = 0.f;
    if (tid < NC) {
        for (int k = 0; k < NC; ++k) {
            float tv = targets[k * NC + tid];
            o0 += iou_pc[0][k] * tv;
            o1 += iou_pc[1][k] * tv;
            o2 += iou_pc[2][k] * tv;
            o3 += iou_pc[3][k] * tv;
        }
    }

    // denominator: wave shfl reduce -> 4 partials -> broadcast sum
    {
        float4 v = (tid < NC) ? make_float4(o0, o1, o2, o3)
                              : make_float4(0.f, 0.f, 0.f, 0.f);
        #pragma unroll
        for (int o = 32; o > 0; o >>= 1) {
            v.x += __shfl_xor(v.x, o);
            v.y += __shfl_xor(v.y, o);
            v.z += __shfl_xor(v.z, o);
            v.w += __shfl_xor(v.w, o);
        }
        if ((tid & 63) == 0) wred[tid >> 6] = v;
    }
    __syncthreads();
    float4 den;
    {
        float4 a = wred[0], b = wred[1], c = wred[2], d = wred[3];
        den = make_float4(a.x + b.x + c.x + d.x, a.y + b.y + c.y + d.y,
                          a.z + b.z + c.z + d.z, a.w + b.w + c.w + d.w);
    }

    if (tid < NC) {
        size_t ob = (size_t)(bkt * 16 + q * 4) * NC + tid;
        out[ob + 0 * NC] = o0 * __builtin_amdgcn_rcpf(den.x);
        out[ob + 1 * NC] = o1 * __builtin_amdgcn_rcpf(den.y);
        out[ob + 2 * NC] = o2 * __builtin_amdgcn_rcpf(den.z);
        out[ob + 3 * NC] = o3 * __builtin_amdgcn_rcpf(den.w);
    }
}

// ---------------------------------------------------------------------------
extern "C" void kernel_launch(void* const* d_in, const int* in_sizes, int n_in,
                              void* d_out, int out_size, void* d_ws, size_t ws_size,
                              hipStream_t stream) {
    const int*   pred    = (const int*)d_in[0];
    const int*   tgt     = (const int*)d_in[1];
    const float* targets = (const float*)d_in[2];
    float*       out     = (float*)d_out;

    // ws layout (nothing needs pre-zeroing):
    u16* recSeg  = (u16*)d_ws;                               // 4.19M u16 = 8.4 MB
    u32* metaArr = (u32*)(recSeg + (size_t)SEGS * SEGPIX);   // 256K u32 = 1 MB
    u16* ntPart  = (u16*)(metaArr + SEGS * PBKT);            // 1024*160 u16 = 320 KB
    u32* gNT     = (u32*)(ntPart + SEGS * 160);              // 2400 u32

    partition_kernel<<<SEGS, 256, 0, stream>>>(pred, tgt, recSeg, metaArr, ntPart);
    ntreduce<<<B_, 256, 0, stream>>>(ntPart, gNT);
    iou_kernel<<<PBKT * 4, 256, 0, stream>>>(recSeg, metaArr, gNT, targets, out);
}

// Round 17
// 54.592 us; speedup vs baseline: 1.6102x; 1.0038x over previous
//
#include <hip/hip_runtime.h>

// Problem constants (fixed by setup_inputs)
#define B_    16
#define N_    262144            // 2^18 pixels per image
#define NC    150               // classes
#define NP    4096              // pred segment ids
#define T_    (B_ * NC)         // 2400 distinct target ids
#define TOTAL (B_ * N_)         // 4,194,304 pixels

#define NSUB   1024             // sub-buckets (pred>>2), 4 pred rows each
#define SEGS   1024             // partition blocks
#define SEGPIX 4096             // pixels (records) per segment
#define QT     9600             // local keys per sub-bucket block (4*2400)

typedef unsigned int u32;
typedef unsigned short u16;

// ---------------------------------------------------------------------------
// Kernel 1: staged radix-split by pred>>2 (1024 bins), single input pass,
// rank-fused, contiguous flush (sort granularity doesn't affect flush).
// Packed dual-u16 LDS counters; meta[(seg,sub)] = (lstart<<16)|cnt written
// as coalesced uint4. Nothing pre-zeroed. LDS ~39 KB -> 4 blocks/CU.
// ---------------------------------------------------------------------------
__global__ __launch_bounds__(256) void partition_kernel(const int* __restrict__ pred,
                                                        const int* __restrict__ tgt,
                                                        u16* __restrict__ recSeg,
                                                        u32* __restrict__ metaArr,
                                                        u16* __restrict__ ntPart) {
    __shared__ u32 keybuf[SEGPIX];   // 16 KB: (sub<<16)|lk
    __shared__ u16 rankbuf[SEGPIX];  // 8 KB: within-(block,sub) rank
    __shared__ u16 staging[SEGPIX];  // 8 KB: sub-bucket-sorted u16 records
    __shared__ u32 cnt32[NSUB / 2];  // 2 KB: two u16 counters per word
    __shared__ u32 lstart[NSUB];     // 4 KB
    __shared__ u32 nth[NC];          // 600 B
    __shared__ u32 wsum[4];

    int tid = threadIdx.x;
    int blk = blockIdx.x;
    cnt32[tid] = 0;
    cnt32[tid + 256] = 0;
    if (tid < NC) nth[tid] = 0;
    __syncthreads();

    int base = blk * SEGPIX;
    int b_img = base >> 18;                  // constant per block
    const int4* pred4 = (const int4*)pred;
    const int4* tgt4  = (const int4*)tgt;

    // ---- phase A: read once; key + rank into LDS; packed counts ----
    #pragma unroll
    for (int k = 0; k < 4; ++k) {
        int vi = (base >> 2) + k * 256 + tid;
        int4 pv = pred4[vi];
        int4 tv = tgt4[vi];
        int pe[4] = {pv.x, pv.y, pv.z, pv.w};
        int te[4] = {tv.x, tv.y, tv.z, tv.w};
        #pragma unroll
        for (int e = 0; e < 4; ++e) {
            int p = pe[e];
            u32 sub = (u32)(p >> 2);
            u32 lk  = (u32)((p & 15) * T_ + b_img * NC + te[e]);
            int flat = (k * 256 + tid) * 4 + e;
            u32 shift = (sub & 1u) * 16u;
            u32 old = atomicAdd(&cnt32[sub >> 1], 1u << shift);
            keybuf[flat]  = (sub << 16) | lk;
            rankbuf[flat] = (u16)((old >> shift) & 0xFFFFu);
            atomicAdd(&nth[te[e]], 1u);
        }
    }
    __syncthreads();

    // ---- phase B: two-level exclusive scan over 1024 counts ----
    {
        u32 w0 = cnt32[2 * tid], w1 = cnt32[2 * tid + 1];
        u32 c0 = w0 & 0xFFFFu, c1 = w0 >> 16, c2 = w1 & 0xFFFFu, c3 = w1 >> 16;
        u32 tot = c0 + c1 + c2 + c3;
        u32 v = tot;
        #pragma unroll
        for (int o = 1; o < 64; o <<= 1) {
            u32 t = __shfl_up(v, o);
            if ((tid & 63) >= o) v += t;
        }
        if ((tid & 63) == 63) wsum[tid >> 6] = v;
        __syncthreads();
        u32 woff = 0;
        #pragma unroll
        for (int w = 0; w < 3; ++w) woff += (w < (tid >> 6)) ? wsum[w] : 0;
        u32 run = v + woff - tot;                // exclusive base for sub 4*tid
        uint4 mv;
        lstart[4 * tid + 0] = run; mv.x = (run << 16) | c0; run += c0;
        lstart[4 * tid + 1] = run; mv.y = (run << 16) | c1; run += c1;
        lstart[4 * tid + 2] = run; mv.z = (run << 16) | c2; run += c2;
        lstart[4 * tid + 3] = run; mv.w = (run << 16) | c3;
        ((uint4*)metaArr)[blk * 256 + tid] = mv;     // coalesced 16 B store
    }
    if (tid < NC) ntPart[blk * 160 + tid] = (u16)nth[tid];
    __syncthreads();

    // ---- phase C: rank-based scatter into staging (no atomics) ----
    #pragma unroll
    for (int k = 0; k < 16; ++k) {
        int flat = tid * 16 + k;
        u32 v = keybuf[flat];
        staging[lstart[v >> 16] + (u32)rankbuf[flat]] = (u16)(v & 0xFFFFu);
    }
    __syncthreads();

    // ---- phase D: contiguous vectorized flush (8 KB as 512 uint4) ----
    {
        const uint4* s4 = (const uint4*)staging;
        uint4* d4 = (uint4*)(recSeg + (size_t)blk * SEGPIX);
        d4[tid]       = s4[tid];
        d4[tid + 256] = s4[tid + 256];
    }
}

// ---------------------------------------------------------------------------
// Kernel 2: reduce nt partials -> gNT. Single-writer, no atomics, no init.
// ---------------------------------------------------------------------------
__global__ __launch_bounds__(256) void ntreduce(const u16* __restrict__ ntPart,
                                                u32* __restrict__ gNT) {
    int img = blockIdx.x;
    int c = threadIdx.x;
    if (c < NC) {
        u32 s = 0;
        #pragma unroll 8
        for (int b2 = 0; b2 < SEGS / B_; ++b2)      // 64 partition blocks per image
            s += ntPart[(img * (SEGS / B_) + b2) * 160 + c];
        gNT[img * NC + c] = s;
    }
}

// ---------------------------------------------------------------------------
// Kernel 3: one block per sub-bucket (4 pred rows). Reads ONLY its own
// per-segment runs (mean ~4 records) via meta -- no filter, scan 1/4 the data.
// LDS ~22 KB -> 7 blocks/CU.
// ---------------------------------------------------------------------------
__global__ __launch_bounds__(256, 7) void iou_kernel(const u16* __restrict__ recSeg,
                                                     const u32* __restrict__ metaArr,
                                                     const u32* __restrict__ gNT,
                                                     const float* __restrict__ targets,
                                                     float* __restrict__ out) {
    __shared__ u32 hist[QT / 2];              // 4800 words = 19.2 KB
    __shared__ float npred_s[4];
    __shared__ float iou_pc[4][NC];           // 2.4 KB
    __shared__ float4 wred[4];                // per-wave partial denominators

    int tid = threadIdx.x;
    int sub = blockIdx.x;                     // 0..1023
    u32 lo = (u32)((sub & 3) * QT);

    // vectorized hist zero
    {
        uint4 z4 = make_uint4(0u, 0u, 0u, 0u);
        uint4* h4 = (uint4*)hist;
        for (int j = tid; j < QT / 8; j += 256) h4[j] = z4;
    }
    __syncthreads();

    // scan: 4 segments per thread, each a ~4-record contiguous run
    for (int s = tid; s < SEGS; s += 256) {
        u32 m  = metaArr[s * NSUB + sub];
        u32 ls = m >> 16;
        u32 n  = m & 0xFFFFu;
        if (!n) continue;
        u32 je = ls + n;
        const u16* segp = recSeg + (size_t)s * SEGPIX;
        for (u32 j = ls & ~7u; j < je; j += 8) {
            uint4 v = *(const uint4*)(segp + j);
            u32 words[4] = {v.x, v.y, v.z, v.w};
            #pragma unroll
            for (int w = 0; w < 4; ++w) {
                #pragma unroll
                for (int h = 0; h < 2; ++h) {
                    u32 idx = j + (u32)(w * 2 + h);
                    if (idx >= ls && idx < je) {
                        u32 lk = ((words[w] >> (h * 16)) & 0xFFFFu) - lo;
                        if (lk < (u32)QT)
                            atomicAdd(&hist[lk >> 1], (lk & 1u) ? 65536u : 1u);
                    }
                }
            }
        }
    }
    __syncthreads();

    // n_pred row sums: 4 waves, one pred row each (1200 words)
    {
        int pl = tid >> 6, lane = tid & 63;
        u32 s = 0;
        for (int w = lane; w < T_ / 2; w += 64) {
            u32 v = hist[pl * (T_ / 2) + w];
            s += (v & 0xFFFFu) + (v >> 16);
        }
        #pragma unroll
        for (int o = 32; o > 0; o >>= 1) s += __shfl_xor(s, o);
        if (lane == 0) npred_s[pl] = (float)s;
    }
    __syncthreads();

    // iou_pc[pl][c] = sum_b O/(n_pred + n_tgt - O); gNT reads are L1-hot
    for (int idx = tid; idx < 4 * NC; idx += 256) {
        int pl = idx / NC, cls = idx - pl * NC;
        float np = npred_s[pl];
        float acc = 0.f;
        #pragma unroll
        for (int b = 0; b < B_; ++b) {
            int lk = pl * T_ + b * NC + cls;
            u32 w = hist[lk >> 1];
            u32 v = (lk & 1) ? (w >> 16) : (w & 0xFFFFu);
            if (v) {
                float fv = (float)v;
                acc += fv * __builtin_amdgcn_rcpf(np + (float)gNT[b * NC + cls] - fv);
            }
        }
        iou_pc[pl][cls] = acc;
    }
    __syncthreads();

    // matmul with targets (each element read once for all 4 rows)
    float o0 = 0.f, o1 = 0.f, o2 = 0.f, o3 = 0.f;
    if (tid < NC) {
        for (int k = 0; k < NC; ++k) {
            float tv = targets[k * NC + tid];
            o0 += iou_pc[0][k] * tv;
            o1 += iou_pc[1][k] * tv;
            o2 += iou_pc[2][k] * tv;
            o3 += iou_pc[3][k] * tv;
        }
    }

    // denominator: wave shfl reduce -> 4 partials -> broadcast sum
    {
        float4 v = (tid < NC) ? make_float4(o0, o1, o2, o3)
                              : make_float4(0.f, 0.f, 0.f, 0.f);
        #pragma unroll
        for (int o = 32; o > 0; o >>= 1) {
            v.x += __shfl_xor(v.x, o);
            v.y += __shfl_xor(v.y, o);
            v.z += __shfl_xor(v.z, o);
            v.w += __shfl_xor(v.w, o);
        }
        if ((tid & 63) == 0) wred[tid >> 6] = v;
    }
    __syncthreads();
    float4 den;
    {
        float4 a = wred[0], b = wred[1], c = wred[2], d = wred[3];
        den = make_float4(a.x + b.x + c.x + d.x, a.y + b.y + c.y + d.y,
                          a.z + b.z + c.z + d.z, a.w + b.w + c.w + d.w);
    }

    if (tid < NC) {
        // preds covered: (sub>>2)*16 + (sub&3)*4 + pl
        size_t ob = (size_t)((sub >> 2) * 16 + (sub & 3) * 4) * NC + tid;
        out[ob + 0 * NC] = o0 * __builtin_amdgcn_rcpf(den.x);
        out[ob + 1 * NC] = o1 * __builtin_amdgcn_rcpf(den.y);
        out[ob + 2 * NC] = o2 * __builtin_amdgcn_rcpf(den.z);
        out[ob + 3 * NC] = o3 * __builtin_amdgcn_rcpf(den.w);
    }
}

// ---------------------------------------------------------------------------
extern "C" void kernel_launch(void* const* d_in, const int* in_sizes, int n_in,
                              void* d_out, int out_size, void* d_ws, size_t ws_size,
                              hipStream_t stream) {
    const int*   pred    = (const int*)d_in[0];
    const int*   tgt     = (const int*)d_in[1];
    const float* targets = (const float*)d_in[2];
    float*       out     = (float*)d_out;

    // ws layout (nothing needs pre-zeroing):
    u16* recSeg  = (u16*)d_ws;                               // 4.19M u16 = 8.4 MB
    u32* metaArr = (u32*)(recSeg + (size_t)SEGS * SEGPIX);   // 1024*1024 u32 = 4 MB
    u16* ntPart  = (u16*)(metaArr + (size_t)SEGS * NSUB);    // 1024*160 u16 = 320 KB
    u32* gNT     = (u32*)(ntPart + SEGS * 160);              // 2400 u32

    partition_kernel<<<SEGS, 256, 0, stream>>>(pred, tgt, recSeg, metaArr, ntPart);
    ntreduce<<<B_, 256, 0, stream>>>(ntPart, gNT);
    iou_kernel<<<NSUB, 256, 0, stream>>>(recSeg, metaArr, gNT, targets, out);
}